// Round 1
// baseline (137.829 us; speedup 1.0000x reference)
//
#include <hip/hip_runtime.h>

#define B_ITEMS 65536

// ---------- helpers ----------
__device__ __forceinline__ float shx(float v, int m) {
    return __shfl_xor(v, m, 64);
}
__device__ __forceinline__ float rdlane(float v, int l) {
    // wave-uniform broadcast from lane l (compile-time constant) -> SGPR
    return __uint_as_float(__builtin_amdgcn_readlane(__float_as_uint(v), l));
}

// ---------- kernel 1: linear layers + outer product -> circuit params ----------
// params_out[i*16 + d*8 + q] = layer[d]*qubit[q] + prev[i][d][q]
__global__ __launch_bounds__(256) void prep_kernel(
    const float* __restrict__ x, const float* __restrict__ prev,
    const float* __restrict__ W_enc, const float* __restrict__ b_enc,
    const float* __restrict__ W_layer, const float* __restrict__ b_layer,
    const float* __restrict__ W_qubit, const float* __restrict__ b_qubit,
    float* __restrict__ params_out)
{
    const int i = blockIdx.x * blockDim.x + threadIdx.x;

    float xi[8];
#pragma unroll
    for (int j = 0; j < 8; ++j) xi[j] = x[i * 8 + j];

    float res[8];
#pragma unroll
    for (int j = 0; j < 8; ++j) {
        float acc = b_enc[j];
#pragma unroll
        for (int k = 0; k < 8; ++k) acc = fmaf(W_enc[j * 8 + k], xi[k], acc);
        res[j] = acc;
    }

    float lay[2];
#pragma unroll
    for (int d = 0; d < 2; ++d) {
        float acc = b_layer[d];
#pragma unroll
        for (int k = 0; k < 8; ++k) acc = fmaf(W_layer[d * 8 + k], res[k], acc);
        lay[d] = acc;
    }

    float qub[8];
#pragma unroll
    for (int j = 0; j < 8; ++j) {
        float acc = b_qubit[j];
#pragma unroll
        for (int k = 0; k < 8; ++k) acc = fmaf(W_qubit[j * 8 + k], res[k], acc);
        qub[j] = acc;
    }

#pragma unroll
    for (int d = 0; d < 2; ++d)
#pragma unroll
        for (int q = 0; q < 8; ++q)
            params_out[i * 16 + d * 8 + q] =
                fmaf(lay[d], qub[q], prev[i * 16 + d * 8 + q]);
}

// ---------- kernel 2: statevector simulation, one wave per item ----------
// Amplitude position p in [0,256): p = lane*4 + r.
// qubit q (0..5) <-> lane bit (5-q); qubit 6 <-> r bit 1; qubit 7 <-> r bit 0.

// RY on lane-bit qubit q with (c,s) broadcast from lane g:
//  0-side: a' = c*a - s*b ; 1-side: a' = c*a + s*b  (b = partner amp)
#define RY_LANE(g, q) { \
    const float c = rdlane(cv, (g)), s = rdlane(sv, (g)); \
    const int m = 1 << (5 - (q)); \
    const float ss = (lane & m) ? s : -s; \
    const float b0 = shx(a0, m), b1 = shx(a1, m); \
    const float b2 = shx(a2, m), b3 = shx(a3, m); \
    a0 = fmaf(c, a0, ss * b0); a1 = fmaf(c, a1, ss * b1); \
    a2 = fmaf(c, a2, ss * b2); a3 = fmaf(c, a3, ss * b3); }

// RY on qubit 6 (r bit 1): pairs (a0,a2),(a1,a3)
#define RY_R6(g) { \
    const float c = rdlane(cv, (g)), s = rdlane(sv, (g)); \
    const float n0 = fmaf(c, a0, -s * a2), n2 = fmaf(c, a2, s * a0); \
    const float n1 = fmaf(c, a1, -s * a3), n3 = fmaf(c, a3, s * a1); \
    a0 = n0; a1 = n1; a2 = n2; a3 = n3; }

// RY on qubit 7 (r bit 0): pairs (a0,a1),(a2,a3)
#define RY_R7(g) { \
    const float c = rdlane(cv, (g)), s = rdlane(sv, (g)); \
    const float n0 = fmaf(c, a0, -s * a1), n1 = fmaf(c, a1, s * a0); \
    const float n2 = fmaf(c, a2, -s * a3), n3 = fmaf(c, a3, s * a2); \
    a0 = n0; a1 = n1; a2 = n2; a3 = n3; }

#define RY_ROUND(G) \
    RY_LANE((G)+0, 0) RY_LANE((G)+1, 1) RY_LANE((G)+2, 2) \
    RY_LANE((G)+3, 3) RY_LANE((G)+4, 4) RY_LANE((G)+5, 5) \
    RY_R6((G)+6) RY_R7((G)+7)

// Even CNOT layer: (0,1)(2,3)(4,5) = one composed lane involution; (6,7) = reg swap
#define CNOT_EVEN { \
    const int src = lane ^ ((lane >> 1) & 21); \
    a0 = __shfl(a0, src, 64); a1 = __shfl(a1, src, 64); \
    a2 = __shfl(a2, src, 64); a3 = __shfl(a3, src, 64); \
    const float t = a2; a2 = a3; a3 = t; }

// Odd CNOT layer: (1,2)(3,4) = lane involution; (5,6): if lane&1 swap (a0,a2),(a1,a3)
#define CNOT_ODD { \
    const int src = lane ^ ((lane >> 1) & 10); \
    a0 = __shfl(a0, src, 64); a1 = __shfl(a1, src, 64); \
    a2 = __shfl(a2, src, 64); a3 = __shfl(a3, src, 64); \
    const bool f = (lane & 1) != 0; \
    const float n0 = f ? a2 : a0, n2 = f ? a0 : a2; \
    const float n1 = f ? a3 : a1, n3 = f ? a1 : a3; \
    a0 = n0; a1 = n1; a2 = n2; a3 = n3; }

__global__ __launch_bounds__(256) void sim_kernel(
    const float* __restrict__ x, const float* __restrict__ params,
    const float* __restrict__ W_post, const float* __restrict__ b_post,
    float* __restrict__ out)
{
    const int lane = threadIdx.x & 63;
    const int item = blockIdx.x * 4 + (threadIdx.x >> 6);

    // lanes 0..7: encoding angles (= batch_item); lanes 8..23: weight angles
    float theta = 0.0f;
    if (lane < 8)       theta = x[item * 8 + lane];
    else if (lane < 24) theta = params[item * 16 + (lane - 8)];
    float sv, cv;
    __sincosf(0.5f * theta, &sv, &cv);

    // |+>^8 after H layer: uniform amplitude 2^-4
    float a0 = 0.0625f, a1 = 0.0625f, a2 = 0.0625f, a3 = 0.0625f;

    RY_ROUND(0)                       // encoding RYs, qubits 0..7
    CNOT_EVEN CNOT_ODD RY_ROUND(8)    // depth 0
    CNOT_EVEN CNOT_ODD RY_ROUND(16)   // depth 1

    // probabilities and <Z_p>, p = 0..3 (lane bits 5,4,3,2)
    float S = a0 * a0 + a1 * a1 + a2 * a2 + a3 * a3;
    S += shx(S, 1);   // sum over qubit 5 (lane bit 0)
    S += shx(S, 2);   // sum over qubit 4 (lane bit 1)

    float e0 = (lane & 32) ? -S : S;
    e0 += shx(e0, 4); e0 += shx(e0, 8); e0 += shx(e0, 16); e0 += shx(e0, 32);
    float e1 = (lane & 16) ? -S : S;
    e1 += shx(e1, 4); e1 += shx(e1, 8); e1 += shx(e1, 16); e1 += shx(e1, 32);
    float e2 = (lane & 8) ? -S : S;
    e2 += shx(e2, 4); e2 += shx(e2, 8); e2 += shx(e2, 16); e2 += shx(e2, 32);
    float e3 = (lane & 4) ? -S : S;
    e3 += shx(e3, 4); e3 += shx(e3, 8); e3 += shx(e3, 16); e3 += shx(e3, 32);

    if (lane == 0) {
        out[item] = b_post[0] + W_post[0] * e0 + W_post[1] * e1
                              + W_post[2] * e2 + W_post[3] * e3;
    }
}

extern "C" void kernel_launch(void* const* d_in, const int* in_sizes, int n_in,
                              void* d_out, int out_size, void* d_ws, size_t ws_size,
                              hipStream_t stream) {
    const float* x       = (const float*)d_in[0];  // [B,8]
    const float* prev    = (const float*)d_in[1];  // [B,2,8]
    const float* W_enc   = (const float*)d_in[2];
    const float* b_enc   = (const float*)d_in[3];
    const float* W_layer = (const float*)d_in[4];
    const float* b_layer = (const float*)d_in[5];
    const float* W_qubit = (const float*)d_in[6];
    const float* b_qubit = (const float*)d_in[7];
    const float* W_post  = (const float*)d_in[8];
    const float* b_post  = (const float*)d_in[9];

    float* out    = (float*)d_out;        // [B,1]
    float* params = out + B_ITEMS;        // [B,2,8] (second output, also sim input)

    prep_kernel<<<B_ITEMS / 256, 256, 0, stream>>>(
        x, prev, W_enc, b_enc, W_layer, b_layer, W_qubit, b_qubit, params);

    sim_kernel<<<B_ITEMS / 4, 256, 0, stream>>>(
        x, params, W_post, b_post, out);
}